// Round 1
// baseline (1262.344 us; speedup 1.0000x reference)
//
#include <hip/hip_runtime.h>

typedef _Float16 half_t;
typedef _Float16 f16x8 __attribute__((ext_vector_type(8)));
typedef float    f32x4 __attribute__((ext_vector_type(4)));

#define MFMA16(a, b, c) __builtin_amdgcn_mfma_f32_16x16x32_f16((a), (b), (c), 0, 0, 0)

struct __align__(4) h2 { half_t a, b; };

__device__ __forceinline__ float gelu_f(float v) {
    return 0.5f * v * (1.0f + erff(v * 0.70710678118654752440f));
}

// ---------------------------------------------------------------------------
// prep: trig tables (fp16) + fc1_w transpose (fp16)
// TT  [64][4096]: c<32: cos(2*pi*c*n/4096) ; c>=32: -sin(...)   (forward DFT B-op)
// ITT [4096][64]: k<32: cos ; k>=32: +sin                        (inverse DFT A-op)
// FC1WT [128][128] = fc1_w^T
// ---------------------------------------------------------------------------
__global__ __launch_bounds__(256) void prep(half_t* __restrict__ TT, half_t* __restrict__ ITT,
                                            half_t* __restrict__ FC1WT, const float* __restrict__ fc1w) {
    int id = blockIdx.x * 256 + threadIdx.x;
    if (id < 262144) {
        int c = id >> 12, n = id & 4095;
        int m = c & 31;
        int ph = (m * n) & 4095;
        float ang = (float)ph * (6.283185307179586f / 4096.0f);
        float cv = cosf(ang), sv = sinf(ang);
        TT[(size_t)c * 4096 + n] = (half_t)((c < 32) ? cv : -sv);
        ITT[(size_t)n * 64 + c]  = (half_t)((c < 32) ? cv : sv);
    } else if (id < 262144 + 16384) {
        int p = id - 262144;
        int j = p >> 7, c = p & 127;
        FC1WT[j * 128 + c] = (half_t)fc1w[c * 128 + j];
    }
}

// ---------------------------------------------------------------------------
// knet1: hg/hl = gelu(y @ {g1,l1}_w + b), stored TRANSPOSED: HGt/HLt [l][k=64][b=32] fp32
// grid 256 = l(4) * b(32) * which(2), block 64
// ---------------------------------------------------------------------------
__global__ __launch_bounds__(64) void knet1(const float* __restrict__ y,
                                            const float* __restrict__ g1w, const float* __restrict__ g1b,
                                            const float* __restrict__ l1w, const float* __restrict__ l1b,
                                            float* __restrict__ HGt, float* __restrict__ HLt) {
    int bid = blockIdx.x;
    int which = bid & 1, b = (bid >> 1) & 31, l = bid >> 6;
    int kp = threadIdx.x;
    const float* w  = (which ? l1w : g1w) + (size_t)l * 256 * 64;
    const float* bb = (which ? l1b : g1b) + l * 64;
    const float* yb = y + b * 256;
    float acc = bb[kp];
    for (int k = 0; k < 256; ++k) acc += yb[k] * w[(size_t)k * 64 + kp];
    float g = gelu_f(acc);
    (which ? HLt : HGt)[((size_t)l * 64 + kp) * 32 + b] = g;
}

// ---------------------------------------------------------------------------
// knet2: WLIN[l][b][o][i] (fp16) = hl[l][b] @ l2_w[l] + l2_b[l]
// grid 512 = l(4)*o(128), block 128 (= i), acc[32] over b
// ---------------------------------------------------------------------------
__global__ __launch_bounds__(128) void knet2(const float* __restrict__ HLt, const float* __restrict__ l2w,
                                             const float* __restrict__ l2b, half_t* __restrict__ WLIN) {
    int l = blockIdx.x >> 7, o = blockIdx.x & 127, i = threadIdx.x;
    float acc[32];
    float bias = l2b[(size_t)l * 16384 + o * 128 + i];
#pragma unroll
    for (int b = 0; b < 32; ++b) acc[b] = bias;
    const float* w = l2w + (size_t)l * 64 * 16384 + o * 128 + i;
    const float* h = HLt + l * 2048;
#pragma unroll 4
    for (int k = 0; k < 64; ++k) {
        float wv = w[(size_t)k * 16384];
        const float* hr = h + k * 32;
#pragma unroll
        for (int b = 0; b < 32; ++b) acc[b] += hr[b] * wv;
    }
#pragma unroll
    for (int b = 0; b < 32; ++b)
        WLIN[(((size_t)l * 32 + b) * 128 + o) * 128 + i] = (half_t)acc[b];
}

// ---------------------------------------------------------------------------
// fc0k: x0 = x_in @ fc0_w + fc0_b ; write XN[b][c][n] and XT[b][n][c] (fp16)
// grid 1024 = b(32)*ntile(32 of 128), block 256
// ---------------------------------------------------------------------------
__global__ __launch_bounds__(256) void fc0k(const float* __restrict__ xin, const float* __restrict__ w,
                                            const float* __restrict__ bias,
                                            half_t* __restrict__ XN, half_t* __restrict__ XT) {
    __shared__ float lx[384];
    int b = blockIdx.x >> 5, nt = blockIdx.x & 31;
    int n0 = nt * 128;
    for (int t = threadIdx.x; t < 384; t += 256) lx[t] = xin[((size_t)b * 4096 + n0) * 3 + t];
    __syncthreads();
#pragma unroll 4
    for (int rr = 0; rr < 32; ++rr) {
        int p = threadIdx.x + rr * 256;       // 8192 slots: c x n-pair
        int c = p >> 6, n2 = (p & 63) * 2;
        float v0 = bias[c] + lx[n2 * 3] * w[c] + lx[n2 * 3 + 1] * w[128 + c] + lx[n2 * 3 + 2] * w[256 + c];
        int n3 = n2 + 1;
        float v1 = bias[c] + lx[n3 * 3] * w[c] + lx[n3 * 3 + 1] * w[128 + c] + lx[n3 * 3 + 2] * w[256 + c];
        h2 hv; hv.a = (half_t)v0; hv.b = (half_t)v1;
        *(h2*)(XN + ((size_t)b * 128 + c) * 4096 + n0 + n2) = hv;
    }
#pragma unroll 4
    for (int rr = 0; rr < 32; ++rr) {
        int p = threadIdx.x + rr * 256;       // n x c-pair
        int n = p >> 6, c2 = (p & 63) * 2;
        float v0 = bias[c2]     + lx[n * 3] * w[c2]     + lx[n * 3 + 1] * w[128 + c2]     + lx[n * 3 + 2] * w[256 + c2];
        float v1 = bias[c2 + 1] + lx[n * 3] * w[c2 + 1] + lx[n * 3 + 1] * w[128 + c2 + 1] + lx[n * 3 + 2] * w[256 + c2 + 1];
        h2 hv; hv.a = (half_t)v0; hv.b = (half_t)v1;
        *(h2*)(XT + ((size_t)b * 4096 + n0 + n) * 128 + c2) = hv;
    }
}

// ---------------------------------------------------------------------------
// fwd_dft: XFTP[ks][row][c] (fp32 partials) = XN[row][k] @ TT[c][k]  (MFMA fp16)
// rows = b*128+i (4096), c = 64 (re:0..31, im:32..63), K split 8x512
// grid (64 row-tiles, 8 ksplit), block 256 (4 waves x 16 rows)
// ---------------------------------------------------------------------------
__global__ __launch_bounds__(256) void fwd_dft(const half_t* __restrict__ XN, const half_t* __restrict__ TT,
                                               float* __restrict__ XFTP) {
    int tile = blockIdx.x, ks = blockIdx.y;
    int wave = threadIdx.x >> 6, lane = threadIdx.x & 63;
    int lm = lane & 15, lq = lane >> 4;
    int r0 = tile * 64 + wave * 16;
    int kbase = ks * 512;
    f32x4 acc[4];
#pragma unroll
    for (int ct = 0; ct < 4; ++ct) acc[ct] = (f32x4){0.f, 0.f, 0.f, 0.f};
    const half_t* arow = XN + (size_t)(r0 + lm) * 4096 + kbase + lq * 8;
#pragma unroll 4
    for (int kk = 0; kk < 16; ++kk) {
        f16x8 a = *(const f16x8*)(arow + kk * 32);
#pragma unroll
        for (int ct = 0; ct < 4; ++ct) {
            const half_t* bp = TT + (size_t)(ct * 16 + lm) * 4096 + kbase + kk * 32 + lq * 8;
            f16x8 bf = *(const f16x8*)bp;
            acc[ct] = MFMA16(a, bf, acc[ct]);
        }
    }
    float* outp = XFTP + (size_t)ks * 262144;
#pragma unroll
    for (int ct = 0; ct < 4; ++ct)
#pragma unroll
        for (int r = 0; r < 4; ++r) {
            int row = r0 + lq * 4 + r;
            outp[(size_t)row * 64 + ct * 16 + lm] = acc[ct][r];
        }
}

__global__ __launch_bounds__(256) void red_xft(const float* __restrict__ XFTP, float* __restrict__ XFT) {
    int i = blockIdx.x * 256 + threadIdx.x;
    float s = 0.f;
#pragma unroll
    for (int p = 0; p < 8; ++p) s += XFTP[(size_t)p * 262144 + i];
    XFT[i] = s;
}

// ---------------------------------------------------------------------------
// spec_w: WSPEC[b][j] (fp16) = hg[b] @ g2_w[l] + g2_b[l] ; j = i*4096 + o*32 + m
// grid 1024 (j-tiles of 512), block 256 = 4 b-groups(8b) x 64 j-groups(8j)
// ---------------------------------------------------------------------------
__global__ __launch_bounds__(256) void spec_w(const float* __restrict__ hg, const float* __restrict__ g2w_l,
                                              const float* __restrict__ g2b_l, half_t* __restrict__ WSPEC) {
    int jg = threadIdx.x & 63;
    int bg = __builtin_amdgcn_readfirstlane((int)(threadIdx.x >> 6));
    int b0 = bg * 8;
    size_t jbase = (size_t)blockIdx.x * 512 + jg * 8;
    float acc[8][8];
#pragma unroll
    for (int i = 0; i < 8; ++i)
#pragma unroll
        for (int q = 0; q < 8; ++q) acc[i][q] = 0.f;
#pragma unroll 4
    for (int k = 0; k < 64; ++k) {
        const float* wr = g2w_l + (size_t)k * 524288 + jbase;
        float4 w0 = *(const float4*)wr;
        float4 w1 = *(const float4*)(wr + 4);
        const float* hr = hg + k * 32 + b0;
#pragma unroll
        for (int bb = 0; bb < 8; ++bb) {
            float h = hr[bb];
            acc[bb][0] += h * w0.x; acc[bb][1] += h * w0.y;
            acc[bb][2] += h * w0.z; acc[bb][3] += h * w0.w;
            acc[bb][4] += h * w1.x; acc[bb][5] += h * w1.y;
            acc[bb][6] += h * w1.z; acc[bb][7] += h * w1.w;
        }
    }
    float4 bv0 = *(const float4*)(g2b_l + jbase);
    float4 bv1 = *(const float4*)(g2b_l + jbase + 4);
    float bvs[8] = {bv0.x, bv0.y, bv0.z, bv0.w, bv1.x, bv1.y, bv1.z, bv1.w};
#pragma unroll
    for (int bb = 0; bb < 8; ++bb) {
        f16x8 hv;
#pragma unroll
        for (int q = 0; q < 8; ++q) hv[q] = (half_t)(acc[bb][q] + bvs[q]);
        *(f16x8*)(WSPEC + (size_t)(b0 + bb) * 524288 + jbase) = hv;
    }
}

// ---------------------------------------------------------------------------
// om_k: om[b][o][m] = sum_i xft[b,i,m] * WSPEC[b,i,o,m]; write OMC[b][o][64] fp16
//   OMC[..][m]    =  c_m * Re(om)
//   OMC[..][32+m] = -c_m * Im(om)
// grid 512 = b(32)*oblk(16 of 8), block 256 = 8o x 32m
// ---------------------------------------------------------------------------
__global__ __launch_bounds__(256) void om_k(const half_t* __restrict__ WSPEC, const float* __restrict__ XFT,
                                            half_t* __restrict__ OMC) {
    __shared__ float xs[128 * 64];
    int b = blockIdx.x >> 4, ob = blockIdx.x & 15;
    for (int t = threadIdx.x; t < 8192; t += 256) xs[t] = XFT[(size_t)b * 8192 + t];
    __syncthreads();
    int o = ob * 8 + (threadIdx.x >> 5), m = threadIdx.x & 31;
    const half_t* wp = WSPEC + (size_t)b * 524288 + o * 32 + m;
    float re = 0.f, im = 0.f;
#pragma unroll 8
    for (int i = 0; i < 128; ++i) {
        float w = (float)wp[(size_t)i * 4096];
        re += w * xs[i * 64 + m];
        im += w * xs[i * 64 + 32 + m];
    }
    float cm = (m == 0) ? (1.0f / 4096.0f) : (2.0f / 4096.0f);
    OMC[((size_t)b * 128 + o) * 64 + m]      = (half_t)(re * cm);
    OMC[((size_t)b * 128 + o) * 64 + 32 + m] = (half_t)(-im * cm);
}

// ---------------------------------------------------------------------------
// layer_out: OUT_T[b][n][o] = sum_k ITT[n][k]*OMC[b][o][k] + sum_i XT[b][n][i]*WLIN[b][o][i]
// epilogue: v=acc/S_l -> (gelu) -> *S_{l+1}; write XT (and XN unless last) in place
// grid 2048 = b(32)*ntile(64 of 64), block 256 (4 waves x 16 n-rows, 8 o-tiles each)
// ---------------------------------------------------------------------------
__global__ __launch_bounds__(256) void layer_out(const half_t* __restrict__ ITT, const half_t* __restrict__ OMC,
                                                 const half_t* __restrict__ WLIN_l,
                                                 half_t* __restrict__ XT, half_t* __restrict__ XN,
                                                 float inv_s, float sout, int do_gelu, int do_xn) {
    __shared__ half_t ts[64 * 130];
    int b = blockIdx.x >> 6, ntile = blockIdx.x & 63;
    int wave = threadIdx.x >> 6, lane = threadIdx.x & 63;
    int lm = lane & 15, lq = lane >> 4;
    int n0w = ntile * 64 + wave * 16;
    f32x4 acc[8];
#pragma unroll
    for (int ot = 0; ot < 8; ++ot) acc[ot] = (f32x4){0.f, 0.f, 0.f, 0.f};

    const half_t* arow1 = ITT + (size_t)(n0w + lm) * 64 + lq * 8;
    const half_t* brow1 = OMC + ((size_t)b * 128 + lm) * 64 + lq * 8;
#pragma unroll
    for (int kk = 0; kk < 2; ++kk) {
        f16x8 a = *(const f16x8*)(arow1 + kk * 32);
#pragma unroll
        for (int ot = 0; ot < 8; ++ot) {
            f16x8 bf = *(const f16x8*)(brow1 + (size_t)ot * 1024 + kk * 32);
            acc[ot] = MFMA16(a, bf, acc[ot]);
        }
    }
    const half_t* arow2 = XT + ((size_t)b * 4096 + n0w + lm) * 128 + lq * 8;
    const half_t* brow2 = WLIN_l + ((size_t)b * 128 + lm) * 128 + lq * 8;
#pragma unroll
    for (int kk = 0; kk < 4; ++kk) {
        f16x8 a = *(const f16x8*)(arow2 + kk * 32);
#pragma unroll
        for (int ot = 0; ot < 8; ++ot) {
            f16x8 bf = *(const f16x8*)(brow2 + (size_t)ot * 2048 + kk * 32);
            acc[ot] = MFMA16(a, bf, acc[ot]);
        }
    }
    // epilogue -> LDS tile [64 n][130 stride] fp16
#pragma unroll
    for (int ot = 0; ot < 8; ++ot) {
        int o = ot * 16 + lm;
#pragma unroll
        for (int r = 0; r < 4; ++r) {
            int n = wave * 16 + lq * 4 + r;
            float v = acc[ot][r] * inv_s;
            if (do_gelu) v = gelu_f(v);
            ts[n * 130 + o] = (half_t)(v * sout);
        }
    }
    __syncthreads();
    // write XT[b][n][o] (in place; this WG owns rows [ntile*64, +64))
#pragma unroll 4
    for (int rr = 0; rr < 16; ++rr) {
        int p = threadIdx.x + rr * 256;
        int n = p >> 6, oc = p & 63;
        uint32_t v = *(const uint32_t*)(ts + n * 130 + 2 * oc);
        *(uint32_t*)(XT + ((size_t)b * 4096 + ntile * 64 + n) * 128 + 2 * oc) = v;
    }
    if (do_xn) {
        int np = threadIdx.x & 31, o8 = threadIdx.x >> 5;
#pragma unroll 4
        for (int rr = 0; rr < 16; ++rr) {
            int o = o8 + 8 * rr;
            int n = 2 * np;
            h2 hv; hv.a = ts[n * 130 + o]; hv.b = ts[(n + 1) * 130 + o];
            *(h2*)(XN + ((size_t)b * 128 + o) * 4096 + ntile * 64 + n) = hv;
        }
    }
}

// ---------------------------------------------------------------------------
// head: out[row] = ( sum_j gelu( (XT[row]/S4) @ fc1w + fc1b )[j] * fc2w[j] + fc2b ) * weightx
// grid 2048 (row-tiles of 64), block 256
// ---------------------------------------------------------------------------
__global__ __launch_bounds__(256) void head(const half_t* __restrict__ XT, const half_t* __restrict__ FC1WT,
                                            const float* __restrict__ fc1b, const float* __restrict__ fc2w,
                                            const float* __restrict__ fc2bias, const float* __restrict__ wx,
                                            float* __restrict__ out, float inv_s) {
    int tile = blockIdx.x;
    int wave = threadIdx.x >> 6, lane = threadIdx.x & 63;
    int lm = lane & 15, lq = lane >> 4;
    int r0 = tile * 64 + wave * 16;
    f32x4 acc[8];
#pragma unroll
    for (int jt = 0; jt < 8; ++jt) acc[jt] = (f32x4){0.f, 0.f, 0.f, 0.f};
    const half_t* arow = XT + (size_t)(r0 + lm) * 128 + lq * 8;
#pragma unroll
    for (int kk = 0; kk < 4; ++kk) {
        f16x8 a = *(const f16x8*)(arow + kk * 32);
#pragma unroll
        for (int jt = 0; jt < 8; ++jt) {
            f16x8 bf = *(const f16x8*)(FC1WT + (size_t)(jt * 16 + lm) * 128 + kk * 32 + lq * 8);
            acc[jt] = MFMA16(a, bf, acc[jt]);
        }
    }
    float sr[4] = {0.f, 0.f, 0.f, 0.f};
#pragma unroll
    for (int jt = 0; jt < 8; ++jt) {
        int j = jt * 16 + lm;
        float b1 = fc1b[j], w2 = fc2w[j];
#pragma unroll
        for (int r = 0; r < 4; ++r) {
            float v = acc[jt][r] * inv_s + b1;
            v = gelu_f(v);
            sr[r] += v * w2;
        }
    }
#pragma unroll
    for (int r = 0; r < 4; ++r) {
        float s = sr[r];
        s += __shfl_xor(s, 1);
        s += __shfl_xor(s, 2);
        s += __shfl_xor(s, 4);
        s += __shfl_xor(s, 8);
        if (lm == 0) {
            int row = r0 + lq * 4 + r;
            out[row] = (s + fc2bias[0]) * wx[0];
        }
    }
}

// ---------------------------------------------------------------------------
extern "C" void kernel_launch(void* const* d_in, const int* in_sizes, int n_in,
                              void* d_out, int out_size, void* d_ws, size_t ws_size,
                              hipStream_t stream) {
    const float* x_in = (const float*)d_in[0];
    const float* y    = (const float*)d_in[1];
    const float* fc0w = (const float*)d_in[2];
    const float* fc0b = (const float*)d_in[3];
    const float* g1w  = (const float*)d_in[4];
    const float* g1b  = (const float*)d_in[5];
    const float* g2w  = (const float*)d_in[6];
    const float* g2b  = (const float*)d_in[7];
    const float* l1w  = (const float*)d_in[8];
    const float* l1b  = (const float*)d_in[9];
    const float* l2w  = (const float*)d_in[10];
    const float* l2b  = (const float*)d_in[11];
    const float* fc1w = (const float*)d_in[12];
    const float* fc1b = (const float*)d_in[13];
    const float* fc2w = (const float*)d_in[14];
    const float* fc2b = (const float*)d_in[15];
    const float* wx   = (const float*)d_in[16];
    float* out = (float*)d_out;

    char* p = (char*)d_ws;
    half_t* XT    = (half_t*)p; p += 33554432;            // [32][4096][128] fp16
    half_t* XN    = (half_t*)p; p += 33554432;            // [32][128][4096] fp16
    half_t* WSPEC = (half_t*)p; p += 33554432;            // [32][524288]   fp16 (per-layer)
    half_t* TT    = (half_t*)p; p += 524288;              // [64][4096]
    half_t* ITT   = (half_t*)p; p += 524288;              // [4096][64]
    half_t* FC1WT = (half_t*)p; p += 32768;               // [128][128]
    float*  HGt   = (float*)p;  p += 32768;               // [4][64][32]
    float*  HLt   = (float*)p;  p += 32768;               // [4][64][32]
    half_t* WLIN  = (half_t*)p; p += 4194304;             // [4][32][128][128]
    float*  XFTP  = (float*)p;  p += 8388608;             // [8][4096][64]
    float*  XFT   = (float*)p;  p += 1048576;             // [4096][64]
    half_t* OMC   = (half_t*)p; p += 524288;              // [32][128][64]

    prep<<<1088, 256, 0, stream>>>(TT, ITT, FC1WT, fc1w);
    knet1<<<256, 64, 0, stream>>>(y, g1w, g1b, l1w, l1b, HGt, HLt);
    knet2<<<512, 128, 0, stream>>>(HLt, l2w, l2b, WLIN);
    fc0k<<<1024, 256, 0, stream>>>(x_in, fc0w, fc0b, XN, XT);

    const float S[5] = {1.f, 16.f, 256.f, 4096.f, 65536.f};
    for (int l = 0; l < 4; ++l) {
        fwd_dft<<<dim3(64, 8), 256, 0, stream>>>(XN, TT, XFTP);
        red_xft<<<1024, 256, 0, stream>>>(XFTP, XFT);
        spec_w<<<1024, 256, 0, stream>>>(HGt + l * 2048, g2w + (size_t)l * 64 * 524288,
                                         g2b + (size_t)l * 524288, WSPEC);
        om_k<<<512, 256, 0, stream>>>(WSPEC, XFT, OMC);
        layer_out<<<2048, 256, 0, stream>>>(ITT, OMC, WLIN + (size_t)l * 524288, XT, XN,
                                            1.0f / S[l], S[l + 1], (l < 3) ? 1 : 0, (l < 3) ? 1 : 0);
    }
    head<<<2048, 256, 0, stream>>>(XT, FC1WT, fc1b, fc2w, fc2b, wx, out, 1.0f / S[4]);
}